// Round 18
// baseline (169.728 us; speedup 1.0000x reference)
//
#include <hip/hip_runtime.h>
#include <hip/hip_bf16.h>
#include <stdint.h>

// Problem constants: NA=NT=1024, A_DIM=E_DIM=128, L=128

typedef short bf16x8 __attribute__((ext_vector_type(8)));
typedef float f32x4  __attribute__((ext_vector_type(4)));

#define GLD16(g, l) __builtin_amdgcn_global_load_lds( \
    (const __attribute__((address_space(1))) void*)(uintptr_t)(g), \
    (__attribute__((address_space(3))) void*)(uintptr_t)(l), 16, 0, 0)

// v_dot2_f32_bf16: acc += v.lo*sel.lo + v.hi*sel.hi  (1 VALU instr)
#define DOT2(acc, val, sel) \
    asm("v_dot2_f32_bf16 %0, %1, %2, %0" : "+v"(acc) : "v"(val), "v"(sel))

static __device__ __forceinline__ uint32_t pk2(float lo, float hi) {
    __hip_bfloat16 h0 = __float2bfloat16(lo), h1 = __float2bfloat16(hi);
    return ((uint32_t)(*(uint16_t*)&h1) << 16) | (uint32_t)(*(uint16_t*)&h0);
}

// ---------------- fused prep: inputs transpose + weight transposes + init ----------------
// b < 1024         : transpose inputs tile
// 1024 <= b < 5120 : per-label 128x128 weight transpose + bf16 cast
//                    W2T[(l*128+a)][e] = Awij2[l][e][a], W1T[(l*128+e)][a] = Awij[l][a][e]
// 5120 <= b < 7168 : init output + bf16 mirrors
__global__ __launch_bounds__(256) void prep_kernel(const int* __restrict__ in,
                                                   int* __restrict__ inT,
                                                   const float* __restrict__ W2,
                                                   const float* __restrict__ W1,
                                                   uint16_t* __restrict__ O2T,
                                                   uint16_t* __restrict__ O1T,
                                                   const float* __restrict__ fa,
                                                   const float* __restrict__ ft,
                                                   float* __restrict__ out,
                                                   uint16_t* __restrict__ srcAb,
                                                   uint16_t* __restrict__ srcTb) {
    __shared__ float tile[32][33];
    int b = blockIdx.x;
    int tx = threadIdx.x & 31, ty = threadIdx.x >> 5;

    if (b < 1024) {                       // ---- transpose inputs ----
        int tr = b >> 5, tc = b & 31;
        int r0 = tr * 32, c0 = tc * 32;
#pragma unroll
        for (int p = 0; p < 4; ++p)
            tile[ty + p * 8][tx] = __int_as_float(in[(size_t)(r0 + ty + p * 8) * 1024 + c0 + tx]);
        __syncthreads();
#pragma unroll
        for (int p = 0; p < 4; ++p) {
            int cc = ty + p * 8;
            inT[(size_t)(c0 + cc) * 1024 + r0 + tx] = __float_as_int(tile[tx][cc]);
        }
    } else if (b < 5120) {                // ---- weight transpose + cast ----
        int bb = b - 1024;
        const float* W = W2;
        uint16_t* O = O2T;
        if (bb >= 2048) { bb -= 2048; W = W1; O = O1T; }
        int l = bb >> 4, sub = bb & 15;
        int x0 = (sub >> 2) * 32, y0 = (sub & 3) * 32;
#pragma unroll
        for (int p = 0; p < 4; ++p)
            tile[ty + p * 8][tx] = W[(size_t)l * 16384 + (size_t)(x0 + ty + p * 8) * 128 + y0 + tx];
        __syncthreads();
#pragma unroll
        for (int p = 0; p < 4; ++p) {
            int yy = ty + p * 8;
            __hip_bfloat16 h = __float2bfloat16(tile[tx][yy]);
            O[(size_t)(l * 128 + y0 + yy) * 128 + x0 + tx] = *(uint16_t*)&h;
        }
    } else {                              // ---- init output + mirrors ----
        int i = (b - 5120) * 256 + threadIdx.x;
        int r = i >> 8, c = i & 255;
        float v = 0.f;
        if (c < 128) {
            v = (r < 1024) ? fa[(size_t)r * 128 + c] : ft[(size_t)(r - 1024) * 128 + c];
            __hip_bfloat16 h = __float2bfloat16(v);
            if (r < 1024) srcAb[(size_t)r * 128 + c] = *(uint16_t*)&h;
            else          srcTb[(size_t)(r - 1024) * 128 + c] = *(uint16_t*)&h;
        }
        out[i] = v;
    }
}

// ---------------- proj: P[1024][16384] = src[1024][128] x WT[16384][128]^T (bf16, K=128) ----------------
// mt = bid&7: XCD x computes/writes the t-row-slab that gather on XCD x reads.
// 8 waves (2x4), wave tile 64x32, swapped-operand MFMA -> C^T fragments.
__global__ __launch_bounds__(512, 2) void proj_kernel(const uint16_t* __restrict__ src,  // [1024][128]
                                                      const uint16_t* __restrict__ WT,   // [16384][128]
                                                      uint16_t* __restrict__ proj) {     // [1024][16384]
    __shared__ uint16_t At[128 * 128];   // 32 KiB, 16B-slot XOR-swizzled by row&15
    __shared__ uint16_t Bt[128 * 128];

    const int tid = threadIdx.x;
    const int lane = tid & 63, wv = tid >> 6;
    const int bid = blockIdx.x;
    const int mt = bid & 7;
    const int nt = bid >> 3;            // 0..127
    const int wr = wv >> 2, wc = wv & 3;

    const int rr = lane >> 4;           // 0..3
    const int sx16 = lane & 15;
#pragma unroll
    for (int g = 0; g < 4; ++g) {
        int row = wv * 16 + g * 4 + rr;
        int sx = sx16 ^ (row & 15);     // pre-swizzled source (involution)
        GLD16((const char*)src + ((size_t)(mt * 128 + row) * 128 + sx * 8) * 2,
              (char*)At + (wv * 16 + g * 4) * 256);
        GLD16((const char*)WT + ((size_t)(nt * 128 + row) * 128 + sx * 8) * 2,
              (char*)Bt + (wv * 16 + g * 4) * 256);
    }
    __syncthreads();   // drains GLD16 vmcnt

    f32x4 acc[4][2] = {};
    const int q = lane >> 4, rl = lane & 15;
#pragma unroll
    for (int kk = 0; kk < 4; ++kk) {
        bf16x8 af[4], bfr[2];
#pragma unroll
        for (int m = 0; m < 4; ++m) {
            int row = wr * 64 + m * 16 + rl;
            int sw = (kk * 4 + q) ^ (row & 15);
            af[m] = *(const bf16x8*)((const char*)At + row * 256 + sw * 16);
        }
#pragma unroll
        for (int n = 0; n < 2; ++n) {
            int row = wc * 32 + n * 16 + rl;
            int sw = (kk * 4 + q) ^ (row & 15);
            bfr[n] = *(const bf16x8*)((const char*)Bt + row * 256 + sw * 16);
        }
#pragma unroll
        for (int m = 0; m < 4; ++m)
#pragma unroll
            for (int n = 0; n < 2; ++n)   // swapped operands -> D = C^T fragment
                acc[m][n] = __builtin_amdgcn_mfma_f32_16x16x32_bf16(bfr[n], af[m], acc[m][n], 0, 0, 0);
    }

    // C^T frag: col(lane&15) = m-space, row(q*4+reg) = n-space -> regs are 4 consecutive n.
#pragma unroll
    for (int m = 0; m < 4; ++m)
#pragma unroll
        for (int n = 0; n < 2; ++n) {
            int mrow = mt * 128 + wr * 64 + m * 16 + rl;
            int ncol = nt * 128 + wc * 32 + n * 16 + q * 4;
            uint2 pk;
            pk.x = pk2(acc[m][n][0], acc[m][n][1]);
            pk.y = pk2(acc[m][n][2], acc[m][n][3]);
            *(uint2*)(proj + (size_t)mrow * 16384 + ncol) = pk;
        }
}

// ---------------- gather partial: partial[j][ts] = sum_{t in slice ts} proj[t, lab[j][t], :] ----------------
// Block (j, ts), bid = j*8+ts -> XCD ts reads its own 4 MiB slice. Labels wave-uniform ->
// readfirstlane + saddr loads, 16 in flight. Channel extract+accumulate via v_dot2_f32_bf16
// (1 instr per channel-acc instead of unpack+add).
__global__ __launch_bounds__(256, 8) void gather_partial_kernel(
    const int* __restrict__ labels,     // [1024][1024]
    const uint32_t* __restrict__ proj,  // [1024][8192] u32 view
    float* __restrict__ partial)        // [1024][8][128]
{
    __shared__ uint16_t lab16[128];
    __shared__ float red[4][128];
    const int bid = blockIdx.x;
    const int j = bid >> 3, ts = bid & 7;
    const int tid = threadIdx.x;
    const int lane = tid & 63, wv = tid >> 6;

    if (tid < 128) lab16[tid] = (uint16_t)labels[(size_t)j * 1024 + ts * 128 + tid];
    __syncthreads();

    const uint32_t lane_u = (uint32_t)lane;
    const uint32_t* tb = proj + (size_t)(ts * 128 + wv * 32) * 8192 + lane_u;
    const uint32_t onesL = 0x00003F80u;  // (bf16 1.0, bf16 0.0) -> selects LOW channel
    const uint32_t onesH = 0x3F800000u;  // (bf16 0.0, bf16 1.0) -> selects HIGH channel
    float a0 = 0.f, a1 = 0.f, b0 = 0.f, b1 = 0.f;
    float c0 = 0.f, c1 = 0.f, d0 = 0.f, d1 = 0.f;

#pragma unroll 1
    for (int i = 0; i < 32; i += 16) {
        int L[16];
#pragma unroll
        for (int g = 0; g < 4; ++g) {
            ushort4 q = *(const ushort4*)&lab16[wv * 32 + i + g * 4];   // wave-uniform ds_read_b64
            L[g * 4 + 0] = __builtin_amdgcn_readfirstlane((int)q.x);
            L[g * 4 + 1] = __builtin_amdgcn_readfirstlane((int)q.y);
            L[g * 4 + 2] = __builtin_amdgcn_readfirstlane((int)q.z);
            L[g * 4 + 3] = __builtin_amdgcn_readfirstlane((int)q.w);
        }
        uint32_t v[16];
#pragma unroll
        for (int e = 0; e < 16; ++e)     // scalar offsets -> saddr loads, 16 in flight
            v[e] = tb[(uint32_t)(i + e) * 8192u + (uint32_t)L[e] * 64u];

        DOT2(a0, v[0], onesL);  DOT2(a1, v[0], onesH);
        DOT2(a0, v[1], onesL);  DOT2(a1, v[1], onesH);
        DOT2(a0, v[2], onesL);  DOT2(a1, v[2], onesH);
        DOT2(a0, v[3], onesL);  DOT2(a1, v[3], onesH);
        DOT2(b0, v[4], onesL);  DOT2(b1, v[4], onesH);
        DOT2(b0, v[5], onesL);  DOT2(b1, v[5], onesH);
        DOT2(b0, v[6], onesL);  DOT2(b1, v[6], onesH);
        DOT2(b0, v[7], onesL);  DOT2(b1, v[7], onesH);
        DOT2(c0, v[8], onesL);  DOT2(c1, v[8], onesH);
        DOT2(c0, v[9], onesL);  DOT2(c1, v[9], onesH);
        DOT2(c0, v[10], onesL); DOT2(c1, v[10], onesH);
        DOT2(c0, v[11], onesL); DOT2(c1, v[11], onesH);
        DOT2(d0, v[12], onesL); DOT2(d1, v[12], onesH);
        DOT2(d0, v[13], onesL); DOT2(d1, v[13], onesH);
        DOT2(d0, v[14], onesL); DOT2(d1, v[14], onesH);
        DOT2(d0, v[15], onesL); DOT2(d1, v[15], onesH);
    }
    float2 pr;
    pr.x = (a0 + b0) + (c0 + d0);
    pr.y = (a1 + b1) + (c1 + d1);
    *(float2*)&red[wv][lane * 2] = pr;
    __syncthreads();

    if (tid < 128) {
        float s = (red[0][tid] + red[1][tid]) + (red[2][tid] + red[3][tid]);
        partial[((size_t)j * 8 + ts) * 128 + tid] = s;
    }
}

// ---------------- reduce 8 slice-partials + update state + emit bf16 mirror ----------------
__global__ __launch_bounds__(256) void reduce_state_kernel(const float* __restrict__ partial,
                                                           float* __restrict__ state,
                                                           uint16_t* __restrict__ mirror) {
    int i = blockIdx.x * 256 + threadIdx.x;   // grid 512 -> 131072
    int j = i >> 7, c = i & 127;
    const float* p = partial + (size_t)j * 1024 + c;
    float s = ((p[0] + p[128]) + (p[256] + p[384])) + ((p[512] + p[640]) + (p[768] + p[896]));
    float v = state[(size_t)j * 256 + c] + s;
    state[(size_t)j * 256 + c] = v;
    __hip_bfloat16 h = __float2bfloat16(v);
    mirror[(size_t)j * 128 + c] = *(uint16_t*)&h;
}

extern "C" void kernel_launch(void* const* d_in, const int* in_sizes, int n_in,
                              void* d_out, int out_size, void* d_ws, size_t ws_size,
                              hipStream_t stream) {
    const int*   inputs  = (const int*)d_in[0];
    const float* first_a = (const float*)d_in[1];
    const float* first_t = (const float*)d_in[2];
    const float* Awij    = (const float*)d_in[3];
    const float* Awij2   = (const float*)d_in[4];
    float* out = (float*)d_out;

    // workspace layout (52 MiB total)
    char* w = (char*)d_ws;
    int*      inputsT = (int*)(w);                      // 4 MiB
    uint16_t* W2T     = (uint16_t*)(w + (4u << 20));    // 4 MiB  [(l,a)][e]
    uint16_t* W1T     = (uint16_t*)(w + (8u << 20));    // 4 MiB  [(l,e)][a]
    uint16_t* srcAb   = (uint16_t*)(w + (12u << 20));   // 256 KiB bf16 mirror of stateA
    uint16_t* srcTb   = (uint16_t*)(w + (12u << 20) + (1u << 19)); // 256 KiB mirror of stateT
    float*    partial = (float*)(w + (13u << 20));      // 4 MiB  [1024][8][128]
    uint16_t* proj16  = (uint16_t*)(w + (20u << 20));   // 32 MiB [1024][16384] bf16
    if (ws_size < (52u << 20)) return;

    float* stateA = out;                 // [1024][256], cols 0..127 live
    float* stateT = out + 1024 * 256;    // [1024][256], cols 0..127 live

    prep_kernel<<<7168, 256, 0, stream>>>(inputs, inputsT, Awij2, Awij, W2T, W1T,
                                          first_a, first_t, out, srcAb, srcTb);

    for (int s = 0; s < 2; ++s) {
        // Phase A: t_proj = t_mirror x W2T^T; a[j] += sum_t t_proj[t, inputs[j,t], :]
        proj_kernel<<<1024, 512, 0, stream>>>(srcTb, W2T, proj16);
        gather_partial_kernel<<<8192, 256, 0, stream>>>(inputs, (const uint32_t*)proj16, partial);
        reduce_state_kernel<<<512, 256, 0, stream>>>(partial, stateA, srcAb);
        // Phase T: a_proj = a_mirror x W1T^T; t[k] += sum_j a_proj[j, inputs[j,k], :]
        proj_kernel<<<1024, 512, 0, stream>>>(srcAb, W1T, proj16);
        gather_partial_kernel<<<8192, 256, 0, stream>>>(inputsT, (const uint32_t*)proj16, partial);
        reduce_state_kernel<<<512, 256, 0, stream>>>(partial, stateT, srcTb);
    }
}